// Round 12
// baseline (69.329 us; speedup 1.0000x reference)
//
#include <hip/hip_runtime.h>
#include <math.h>

// Problem constants (ProbAttention: B=4, H=8, L=2048, D=64, factor=5)
#define B_ 4
#define H_ 8
#define L_ 2048
#define D_ 64
#define SK_ 40      // sample_k = 5*ceil(ln(2048)) = 40
#define U_ 40       // u = min(5*ceil(ln(2048)), 2048) = 40
#define CK 256      // keys per chunk in batched attention
#define NCHUNK (L_ / CK)   // 8
#define QG 8        // queries per attention block
#define NQG (U_ / QG)      // 5
#define CSB 32      // segsum blocks in k_mcs (one per bh), dispatched FIRST
#define SEG 64      // cumsum segment length
#define NSEGS (L_ / SEG)   // 32 segments per head
#define CSB2 256    // cumsum phase-B blocks in the attn launch (8 per bh)

// ---------------------------------------------------------------------------
// Kernel 1 (v8): heterogeneous fused launch.
//  blocks 0..31   : cumsum PHASE A - per-head segment sums of V (read-only,
//                   16KB of writes; the 16.6MB cumsum write that was
//                   extending this kernel's tail is gone -> phase B)
//  blocks 32..4127: M-score blocks (v6 structure, at the measured
//                   random-gather floor; blk = blockIdx-32, 32%8==0 keeps
//                   the XCD mapping)
// ---------------------------------------------------------------------------
__global__ __launch_bounds__(1024) void k_mcs(
    const float* __restrict__ Q, const float* __restrict__ K,
    const int* __restrict__ idxs, const float* __restrict__ V,
    float* __restrict__ M, float* __restrict__ segsum) {
  if (blockIdx.x < CSB) {
    // ---- phase A: 16 waves x 2 segments of 64 rows, lane = dim
    int bh = blockIdx.x;
    int wv = threadIdx.x >> 6;
    int lane = threadIdx.x & 63;
    const float* Vb = V + (size_t)bh * L_ * D_;
#pragma unroll
    for (int si = 0; si < 2; ++si) {
      int seg = wv * 2 + si;           // 0..31
      int base = seg * SEG;
      float s = 0.f;
      for (int l = 0; l < SEG; ++l) s += Vb[(size_t)(base + l) * D_ + lane];
      segsum[((size_t)bh * NSEGS + seg) * D_ + lane] = s;
    }
    return;
  }

  // ---- M-score path (v6 structure)
  int blk = blockIdx.x - CSB;      // 0..4095
  int x = blk & 7;                 // intended XCD (dispatch round-robins %8)
  int j = blk >> 3;                // 0..511
  int bh = ((j >> 7) << 3) | x;    // 4 heads per XCD-group; K stays in L2
  int qc = j & 127;                // query-chunk within head
  int wave = threadIdx.x >> 6;     // 0..15
  int lane = threadIdx.x & 63;
  int q = qc * 16 + wave;

  int g  = lane >> 3;              // sample group 0..7
  int li = lane & 7;               // lane within group

  const float4* qrow = (const float4*)(Q + ((size_t)bh * L_ + q) * D_);
  float4 qa = qrow[li], qb = qrow[li + 8];
  int myidx = (lane < SK_) ? idxs[q * SK_ + lane] : 0;
  const float* Kb = K + (size_t)bh * L_ * D_;

  int kis[5];
#pragma unroll
  for (int t = 0; t < 5; ++t) kis[t] = __shfl(myidx, t * 8 + g, 64);

  float4 ka[5], kb[5];
#pragma unroll
  for (int t = 0; t < 5; ++t) {
    const float4* kr = (const float4*)(Kb + (size_t)kis[t] * D_);
    ka[t] = kr[li];
    kb[t] = kr[li + 8];
  }

  float d[5];
#pragma unroll
  for (int t = 0; t < 5; ++t) {
    d[t] = qa.x * ka[t].x + qa.y * ka[t].y + qa.z * ka[t].z + qa.w * ka[t].w
         + qb.x * kb[t].x + qb.y * kb[t].y + qb.z * kb[t].z + qb.w * kb[t].w;
  }
  float mx = -INFINITY, sm = 0.f;
#pragma unroll
  for (int t = 0; t < 5; ++t) {
    float v = d[t];
    v += __shfl_xor(v, 1, 64);
    v += __shfl_xor(v, 2, 64);
    v += __shfl_xor(v, 4, 64);     // all 8 lanes of group hold full dot
    mx = fmaxf(mx, v);
    sm += v;
  }
  mx = fmaxf(mx, __shfl_xor(mx, 8, 64));
  mx = fmaxf(mx, __shfl_xor(mx, 16, 64));
  mx = fmaxf(mx, __shfl_xor(mx, 32, 64));
  sm += __shfl_xor(sm, 8, 64);
  sm += __shfl_xor(sm, 16, 64);
  sm += __shfl_xor(sm, 32, 64);
  if (lane == 0) M[bh * L_ + q] = mx - sm * (1.0f / (float)L_);
}

// ---------------------------------------------------------------------------
// Kernel 2 (v2): top-U_ per head via 4-pass MSD radix select.
// ---------------------------------------------------------------------------
__global__ __launch_bounds__(1024) void k_topk(
    const float* __restrict__ M, int* __restrict__ Mtop) {
  __shared__ unsigned keys[L_];    // 8 KB
  __shared__ int hist[256];
  __shared__ int Gs[256];
  __shared__ unsigned ctl_prefix;
  __shared__ int ctl_need, ctl_cnt, ctl_min;
  __shared__ int wmin[16];
  int bh = blockIdx.x;
  int tid = threadIdx.x;

  for (int i = tid; i < L_; i += 1024) {
    unsigned u = __float_as_uint(M[bh * L_ + i]);
    keys[i] = (u & 0x80000000u) ? ~u : (u | 0x80000000u);
  }
  if (tid == 0) { ctl_prefix = 0u; ctl_need = U_; ctl_cnt = 0; }
  __syncthreads();

  unsigned prefix = 0u, pmask = 0u;
#pragma unroll
  for (int pass = 0; pass < 4; ++pass) {
    int shift = 24 - 8 * pass;
    if (tid < 256) hist[tid] = 0;
    __syncthreads();
    for (int i = tid; i < L_; i += 1024) {
      unsigned k = keys[i];
      if ((k & pmask) == prefix) atomicAdd(&hist[(k >> shift) & 0xffu], 1);
    }
    __syncthreads();
    if (tid < 64) {
      int b0 = tid * 4;
      int h0 = hist[b0], h1 = hist[b0 + 1], h2 = hist[b0 + 2], h3 = hist[b0 + 3];
      int gs = h0 + h1 + h2 + h3;
      int S = gs;
#pragma unroll
      for (int d = 1; d < 64; d <<= 1) {
        int v = __shfl_down(S, d, 64);
        if (tid + d < 64) S += v;
      }
      int E = S - gs;              // keys in groups strictly after this group
      Gs[b0 + 3] = E;
      Gs[b0 + 2] = E + h3;
      Gs[b0 + 1] = E + h3 + h2;
      Gs[b0 + 0] = E + h3 + h2 + h1;
    }
    __syncthreads();
    int need = ctl_need;
    if (tid < 256) {
      int G = Gs[tid], h = hist[tid];
      if (G < need && need <= G + h) {   // unique bin
        ctl_prefix = prefix | ((unsigned)tid << shift);
        ctl_need = need - G;
      }
    }
    __syncthreads();
    prefix = ctl_prefix;
    pmask |= (0xffu << shift);
  }

  unsigned v40 = prefix;           // exact 40th-largest key
  int tiesNeeded = ctl_need;
  __syncthreads();

  for (int i = tid; i < L_; i += 1024) {
    if (keys[i] > v40) {
      int slot = atomicAdd(&ctl_cnt, 1);
      Mtop[bh * U_ + slot] = i;
    }
  }
  __syncthreads();
  int base = ctl_cnt;
  int last = -1;
  for (int t = 0; t < tiesNeeded; ++t) {
    int lmin = 0x7fffffff;
    for (int i = tid; i < L_; i += 1024)
      if (keys[i] == v40 && i > last) lmin = min(lmin, i);
#pragma unroll
    for (int d = 32; d > 0; d >>= 1) lmin = min(lmin, __shfl_xor(lmin, d, 64));
    if ((tid & 63) == 0) wmin[tid >> 6] = lmin;
    __syncthreads();
    if (tid == 0) {
      int m = wmin[0];
      for (int w = 1; w < 16; ++w) m = min(m, wmin[w]);
      Mtop[bh * U_ + base + t] = m;
      ctl_min = m;
    }
    __syncthreads();
    last = ctl_min;
  }
}

// ---------------------------------------------------------------------------
// Kernel 4a (v3): heterogeneous launch.
//  blocks 0..255   : cumsum PHASE B - per-(bh, octant) cumsum of V using the
//                    phase-A segment sums; writes out (B,L,H,D). Independent
//                    of Mtop; streams ~34MB hidden under the attn blocks.
//  blocks 256..1535: batched causal attention partials (R11 structure;
//                    blk-256 keeps the &7 XCD mapping since 256%8==0)
// ---------------------------------------------------------------------------
__global__ __launch_bounds__(256) void k_attn_part(
    const float* __restrict__ Q, const float* __restrict__ K,
    const float* __restrict__ V, const int* __restrict__ Mtop,
    const float* __restrict__ segsum,
    float* __restrict__ pm, float* __restrict__ ps, float* __restrict__ pacc,
    float* __restrict__ out) {
  if (blockIdx.x < CSB2) {
    // ---- phase B: block (bh, octant), 4 waves x 1 segment of 64 rows
    int bid = blockIdx.x;
    int bh = bid >> 3, o = bid & 7;
    int b = bh >> 3, h = bh & 7;
    int wv = threadIdx.x >> 6;
    int lane = threadIdx.x & 63;
    int seg = o * 4 + wv;              // 0..31
    float run = 0.f;
    for (int s2 = 0; s2 < seg; ++s2)
      run += segsum[((size_t)bh * NSEGS + s2) * D_ + lane];
    const float* Vb = V + (size_t)bh * L_ * D_;
    int base = seg * SEG;
    for (int l = 0; l < SEG; ++l) {
      int gl = base + l;
      run += Vb[(size_t)gl * D_ + lane];
      out[(((size_t)b * L_ + gl) * H_ + h) * D_ + lane] = run;
    }
    return;
  }

  // ---- attention partials (R11 structure)
  int blk = blockIdx.x - CSB2;     // 0..1279
  int x = blk & 7;
  int j = blk >> 3;                // 0..159
  int bh = (j / 40) * 8 + x;
  int rem = j % 40;
  int c  = rem / NQG;              // K-chunk 0..7
  int qg = rem % NQG;              // query group 0..4

  int tid = threadIdx.x;
  int w = tid >> 6, lane = tid & 63;
  __shared__ float Qs[QG][D_];         // 2 KB
  __shared__ float P[QG][CK];          // 8 KB
  __shared__ float pvred[4][QG][D_];   // 8 KB
  __shared__ int q0s[QG];
  if (tid < QG) q0s[tid] = Mtop[bh * U_ + qg * QG + tid];
  __syncthreads();
  for (int i = tid; i < QG * D_; i += 256) {
    int u = i >> 6, d = i & 63;
    Qs[u][d] = Q[((size_t)bh * L_ + q0s[u]) * D_ + d];
  }
  __syncthreads();

  // phase 1: scores. thread owns key kg = c*CK + tid.
  int kg = c * CK + tid;
  const float4* kr = (const float4*)(K + ((size_t)bh * L_ + kg) * D_);
  float4 kv[16];
#pragma unroll
  for (int j4 = 0; j4 < 16; ++j4) kv[j4] = kr[j4];
#pragma unroll
  for (int u = 0; u < QG; ++u) {
    float acc = 0.f;
#pragma unroll
    for (int j4 = 0; j4 < 16; ++j4) {
      float4 qv = *(const float4*)&Qs[u][j4 * 4];
      acc += qv.x * kv[j4].x + qv.y * kv[j4].y + qv.z * kv[j4].z + qv.w * kv[j4].w;
    }
    P[u][tid] = (kg <= q0s[u]) ? acc : -INFINITY;
  }
  __syncthreads();

  // phase 2: wave w softmaxes queries 2w, 2w+1 (chunk-local m, s)
#pragma unroll
  for (int uu = 0; uu < 2; ++uu) {
    int u = w * 2 + uu;
    float v0 = P[u][lane], v1 = P[u][lane + 64];
    float v2 = P[u][lane + 128], v3 = P[u][lane + 192];
    float m = fmaxf(fmaxf(v0, v1), fmaxf(v2, v3));
    for (int o = 32; o > 0; o >>= 1) m = fmaxf(m, __shfl_xor(m, o, 64));
    float e0 = (v0 == -INFINITY) ? 0.f : expf(v0 - m);
    float e1 = (v1 == -INFINITY) ? 0.f : expf(v1 - m);
    float e2 = (v2 == -INFINITY) ? 0.f : expf(v2 - m);
    float e3 = (v3 == -INFINITY) ? 0.f : expf(v3 - m);
    float s = e0 + e1 + e2 + e3;
    for (int o = 32; o > 0; o >>= 1) s += __shfl_xor(s, o, 64);
    P[u][lane] = e0; P[u][lane + 64] = e1;
    P[u][lane + 128] = e2; P[u][lane + 192] = e3;
    if (lane == 0) {
      int p = (bh * NCHUNK + c) * U_ + qg * QG + u;
      pm[p] = m; ps[p] = s;
    }
  }
  __syncthreads();

  // phase 3: wave w covers keys [c*CK + w*64, +64) for all 8 queries, lane=d
  const float* Vb = V + ((size_t)bh * L_ + c * CK + w * 64) * D_;
  float acc[QG];
#pragma unroll
  for (int u = 0; u < QG; ++u) acc[u] = 0.f;
  for (int k4 = 0; k4 < 16; ++k4) {
    float4 pv[QG];
#pragma unroll
    for (int u = 0; u < QG; ++u) pv[u] = *(const float4*)&P[u][w * 64 + k4 * 4];
    float va = Vb[(size_t)(k4 * 4 + 0) * D_ + lane];
    float vb = Vb[(size_t)(k4 * 4 + 1) * D_ + lane];
    float vc = Vb[(size_t)(k4 * 4 + 2) * D_ + lane];
    float vd = Vb[(size_t)(k4 * 4 + 3) * D_ + lane];
#pragma unroll
    for (int u = 0; u < QG; ++u)
      acc[u] += pv[u].x * va + pv[u].y * vb + pv[u].z * vc + pv[u].w * vd;
  }
#pragma unroll
  for (int u = 0; u < QG; ++u) pvred[w][u][lane] = acc[u];
  __syncthreads();
  // final: wave w writes queries 2w, 2w+1
#pragma unroll
  for (int uu = 0; uu < 2; ++uu) {
    int u = w * 2 + uu;
    float tot = pvred[0][u][lane] + pvred[1][u][lane] +
                pvred[2][u][lane] + pvred[3][u][lane];
    int p = (bh * NCHUNK + c) * U_ + qg * QG + u;
    pacc[(size_t)p * 64 + lane] = tot;
  }
}

// ---------------------------------------------------------------------------
// Kernel 4b: merge chunk partials, normalize, scatter into out.
// ---------------------------------------------------------------------------
__global__ __launch_bounds__(256) void k_attn_reduce(
    const float* __restrict__ pm, const float* __restrict__ ps,
    const float* __restrict__ pacc, const int* __restrict__ Mtop,
    float* __restrict__ out) {
  int g = blockIdx.x * 4 + (threadIdx.x >> 6);  // (bh, u) pair
  int lane = threadIdx.x & 63;
  int bh = g / U_, u = g % U_;
  int b = bh >> 3, h = bh & 7;
  int q0 = Mtop[bh * U_ + u];
  float pmv[NCHUNK];
  float M = -INFINITY;
#pragma unroll
  for (int c = 0; c < NCHUNK; ++c) {
    pmv[c] = pm[(bh * NCHUNK + c) * U_ + u];
    M = fmaxf(M, pmv[c]);
  }
  float T = 0.f, o = 0.f;
#pragma unroll
  for (int c = 0; c < NCHUNK; ++c) {
    float wgt = (pmv[c] == -INFINITY) ? 0.f : expf(pmv[c] - M);
    T += ps[(bh * NCHUNK + c) * U_ + u] * wgt;
    o += pacc[((size_t)(bh * NCHUNK + c) * U_ + u) * 64 + lane] * wgt;
  }
  out[(((size_t)b * L_ + q0) * H_ + h) * D_ + lane] = o / T;
}

extern "C" void kernel_launch(void* const* d_in, const int* in_sizes, int n_in,
                              void* d_out, int out_size, void* d_ws, size_t ws_size,
                              hipStream_t stream) {
  const float* Q = (const float*)d_in[0];
  const float* K = (const float*)d_in[1];
  const float* V = (const float*)d_in[2];
  const int* idxs = (const int*)d_in[3];
  float* out = (float*)d_out;

  char* ws = (char*)d_ws;
  float* M      = (float*)(ws + 0);              // 256 KB
  float* segsum = (float*)(ws + 262144);         // 256 KB (32*32*64 floats)
  int*   Mtop   = (int*)(ws + 524288);           // 5 KB (pad to 8 KB)
  float* pm     = (float*)(ws + 532480);         // 40 KB
  float* ps     = (float*)(ws + 573440);         // 40 KB
  float* pacc   = (float*)(ws + 614400);         // 2.62 MB

  // 1) fused: V segment-sums (blocks 0..31) + M scores
  k_mcs<<<CSB + (B_ * H_ * L_) / 16, 1024, 0, stream>>>(Q, K, idxs, V, M, segsum);
  // 2) top-k per head (radix select)
  k_topk<<<B_ * H_, 1024, 0, stream>>>(M, Mtop);
  // 3) fused: V-cumsum phase B (blocks 0..255, independent of Mtop) +
  //    batched causal attention partials
  k_attn_part<<<CSB2 + B_ * H_ * NCHUNK * NQG, 256, 0, stream>>>(
      Q, K, V, Mtop, segsum, pm, ps, pacc, out);
  // 4) merge partials, overwrite selected rows
  k_attn_reduce<<<(B_ * H_ * U_) / 4, 256, 0, stream>>>(pm, ps, pacc, Mtop, out);
}

// Round 13
// 68.441 us; speedup vs baseline: 1.0130x; 1.0130x over previous
//
#include <hip/hip_runtime.h>
#include <math.h>

// Problem constants (ProbAttention: B=4, H=8, L=2048, D=64, factor=5)
#define B_ 4
#define H_ 8
#define L_ 2048
#define D_ 64
#define SK_ 40      // sample_k = 5*ceil(ln(2048)) = 40
#define U_ 40       // u = min(5*ceil(ln(2048)), 2048) = 40
#define CK 256      // keys per chunk in batched attention
#define NCHUNK (L_ / CK)   // 8
#define QG 8        // queries per attention block
#define NQG (U_ / QG)      // 5
#define CSB 32      // prefix blocks in k_mcs (one per bh), dispatched FIRST
#define SEG2 16     // cumsum segment length (fine-grained for parallel B)
#define NSEG2 (L_ / SEG2)  // 128 segments per head
#define PB 256      // phase-B blocks riding in the topk launch (8 per bh)

// ---------------------------------------------------------------------------
// Kernel 1 (v9): heterogeneous fused launch.
//  blocks 0..31   : cumsum PHASE A - per-head EXCLUSIVE PREFIX of 16-row
//                   segment sums (two-level wave scan in LDS; 1MB table out)
//  blocks 32..4127: M-score blocks (v6 structure, at the measured
//                   random-gather floor; 32%8==0 keeps XCD mapping)
// ---------------------------------------------------------------------------
__global__ __launch_bounds__(1024) void k_mcs(
    const float* __restrict__ Q, const float* __restrict__ K,
    const int* __restrict__ idxs, const float* __restrict__ V,
    float* __restrict__ M, float* __restrict__ pfx) {
  if (blockIdx.x < CSB) {
    // ---- phase A: wave w covers rows [w*128,(w+1)*128) = 8 segs of 16
    __shared__ float wt[16][64];
    int bh = blockIdx.x;
    int w = threadIdx.x >> 6, lane = threadIdx.x & 63;
    const float* Vb = V + (size_t)bh * L_ * D_;
    float pres[8];
    float pre = 0.f;
#pragma unroll
    for (int i = 0; i < 8; ++i) {
      int base = w * 128 + i * SEG2;
      float s = 0.f;
      for (int l = 0; l < SEG2; ++l) s += Vb[(size_t)(base + l) * D_ + lane];
      pres[i] = pre;               // exclusive local prefix
      pre += s;
    }
    wt[w][lane] = pre;             // wave total
    __syncthreads();
    float base = 0.f;
    for (int ww = 0; ww < 16; ++ww) {
      float v = wt[ww][lane];
      if (ww < w) base += v;
    }
#pragma unroll
    for (int i = 0; i < 8; ++i)
      pfx[((size_t)bh * NSEG2 + w * 8 + i) * D_ + lane] = base + pres[i];
    return;
  }

  // ---- M-score path (v6 structure)
  int blk = blockIdx.x - CSB;      // 0..4095
  int x = blk & 7;                 // intended XCD (dispatch round-robins %8)
  int j = blk >> 3;                // 0..511
  int bh = ((j >> 7) << 3) | x;    // 4 heads per XCD-group; K stays in L2
  int qc = j & 127;                // query-chunk within head
  int wave = threadIdx.x >> 6;     // 0..15
  int lane = threadIdx.x & 63;
  int q = qc * 16 + wave;

  int g  = lane >> 3;              // sample group 0..7
  int li = lane & 7;               // lane within group

  const float4* qrow = (const float4*)(Q + ((size_t)bh * L_ + q) * D_);
  float4 qa = qrow[li], qb = qrow[li + 8];
  int myidx = (lane < SK_) ? idxs[q * SK_ + lane] : 0;
  const float* Kb = K + (size_t)bh * L_ * D_;

  int kis[5];
#pragma unroll
  for (int t = 0; t < 5; ++t) kis[t] = __shfl(myidx, t * 8 + g, 64);

  float4 ka[5], kb[5];
#pragma unroll
  for (int t = 0; t < 5; ++t) {
    const float4* kr = (const float4*)(Kb + (size_t)kis[t] * D_);
    ka[t] = kr[li];
    kb[t] = kr[li + 8];
  }

  float d[5];
#pragma unroll
  for (int t = 0; t < 5; ++t) {
    d[t] = qa.x * ka[t].x + qa.y * ka[t].y + qa.z * ka[t].z + qa.w * ka[t].w
         + qb.x * kb[t].x + qb.y * kb[t].y + qb.z * kb[t].z + qb.w * kb[t].w;
  }
  float mx = -INFINITY, sm = 0.f;
#pragma unroll
  for (int t = 0; t < 5; ++t) {
    float v = d[t];
    v += __shfl_xor(v, 1, 64);
    v += __shfl_xor(v, 2, 64);
    v += __shfl_xor(v, 4, 64);     // all 8 lanes of group hold full dot
    mx = fmaxf(mx, v);
    sm += v;
  }
  mx = fmaxf(mx, __shfl_xor(mx, 8, 64));
  mx = fmaxf(mx, __shfl_xor(mx, 16, 64));
  mx = fmaxf(mx, __shfl_xor(mx, 32, 64));
  sm += __shfl_xor(sm, 8, 64);
  sm += __shfl_xor(sm, 16, 64);
  sm += __shfl_xor(sm, 32, 64);
  if (lane == 0) M[bh * L_ + q] = mx - sm * (1.0f / (float)L_);
}

// ---------------------------------------------------------------------------
// Kernel 2 (v3): heterogeneous launch.
//  blocks 0..31  : top-U_ radix select per head (unchanged logic)
//  blocks 32..287: cumsum PHASE B - wave per (bh, 16-row segment), reads the
//                  phase-A prefix + V, writes out (B,L,H,D). Independent of
//                  topk; hides under it (topk uses 32 CUs, B uses the rest).
// ---------------------------------------------------------------------------
__global__ __launch_bounds__(1024) void k_topk(
    const float* __restrict__ M, const float* __restrict__ V,
    const float* __restrict__ pfx, int* __restrict__ Mtop,
    float* __restrict__ out) {
  if (blockIdx.x >= CSB) {
    // ---- phase B
    int bid = blockIdx.x - CSB;    // 0..255
    int bh = bid >> 3, oct = bid & 7;
    int b = bh >> 3, h = bh & 7;
    int w = threadIdx.x >> 6, lane = threadIdx.x & 63;
    int seg = oct * 16 + w;        // 0..127
    float run = pfx[((size_t)bh * NSEG2 + seg) * D_ + lane];
    const float* Vb = V + (size_t)bh * L_ * D_;
    int base = seg * SEG2;
    for (int l = 0; l < SEG2; ++l) {
      int gl = base + l;
      run += Vb[(size_t)gl * D_ + lane];
      out[(((size_t)b * L_ + gl) * H_ + h) * D_ + lane] = run;
    }
    return;
  }

  __shared__ unsigned keys[L_];    // 8 KB
  __shared__ int hist[256];
  __shared__ int Gs[256];
  __shared__ unsigned ctl_prefix;
  __shared__ int ctl_need, ctl_cnt, ctl_min;
  __shared__ int wmin[16];
  int bh = blockIdx.x;
  int tid = threadIdx.x;

  for (int i = tid; i < L_; i += 1024) {
    unsigned u = __float_as_uint(M[bh * L_ + i]);
    keys[i] = (u & 0x80000000u) ? ~u : (u | 0x80000000u);
  }
  if (tid == 0) { ctl_prefix = 0u; ctl_need = U_; ctl_cnt = 0; }
  __syncthreads();

  unsigned prefix = 0u, pmask = 0u;
#pragma unroll
  for (int pass = 0; pass < 4; ++pass) {
    int shift = 24 - 8 * pass;
    if (tid < 256) hist[tid] = 0;
    __syncthreads();
    for (int i = tid; i < L_; i += 1024) {
      unsigned k = keys[i];
      if ((k & pmask) == prefix) atomicAdd(&hist[(k >> shift) & 0xffu], 1);
    }
    __syncthreads();
    if (tid < 64) {
      int b0 = tid * 4;
      int h0 = hist[b0], h1 = hist[b0 + 1], h2 = hist[b0 + 2], h3 = hist[b0 + 3];
      int gs = h0 + h1 + h2 + h3;
      int S = gs;
#pragma unroll
      for (int d = 1; d < 64; d <<= 1) {
        int v = __shfl_down(S, d, 64);
        if (tid + d < 64) S += v;
      }
      int E = S - gs;              // keys in groups strictly after this group
      Gs[b0 + 3] = E;
      Gs[b0 + 2] = E + h3;
      Gs[b0 + 1] = E + h3 + h2;
      Gs[b0 + 0] = E + h3 + h2 + h1;
    }
    __syncthreads();
    int need = ctl_need;
    if (tid < 256) {
      int G = Gs[tid], h = hist[tid];
      if (G < need && need <= G + h) {   // unique bin
        ctl_prefix = prefix | ((unsigned)tid << shift);
        ctl_need = need - G;
      }
    }
    __syncthreads();
    prefix = ctl_prefix;
    pmask |= (0xffu << shift);
  }

  unsigned v40 = prefix;           // exact 40th-largest key
  int tiesNeeded = ctl_need;
  __syncthreads();

  for (int i = tid; i < L_; i += 1024) {
    if (keys[i] > v40) {
      int slot = atomicAdd(&ctl_cnt, 1);
      Mtop[bh * U_ + slot] = i;
    }
  }
  __syncthreads();
  int base = ctl_cnt;
  int last = -1;
  for (int t = 0; t < tiesNeeded; ++t) {
    int lmin = 0x7fffffff;
    for (int i = tid; i < L_; i += 1024)
      if (keys[i] == v40 && i > last) lmin = min(lmin, i);
#pragma unroll
    for (int d = 32; d > 0; d >>= 1) lmin = min(lmin, __shfl_xor(lmin, d, 64));
    if ((tid & 63) == 0) wmin[tid >> 6] = lmin;
    __syncthreads();
    if (tid == 0) {
      int m = wmin[0];
      for (int w = 1; w < 16; ++w) m = min(m, wmin[w]);
      Mtop[bh * U_ + base + t] = m;
      ctl_min = m;
    }
    __syncthreads();
    last = ctl_min;
  }
}

// ---------------------------------------------------------------------------
// Kernel 4a (v2): batched causal attention partials (pure, R11 form).
// One block per (bh, K-chunk, query-group of 8). 1280 blocks.
// ---------------------------------------------------------------------------
__global__ __launch_bounds__(256) void k_attn_part(
    const float* __restrict__ Q, const float* __restrict__ K,
    const float* __restrict__ V, const int* __restrict__ Mtop,
    float* __restrict__ pm, float* __restrict__ ps, float* __restrict__ pacc) {
  // XCD-chunked mapping: all 40 blocks of a head on one XCD (4 heads/XCD)
  int blk = blockIdx.x;            // 0..1279
  int x = blk & 7;
  int j = blk >> 3;                // 0..159
  int bh = (j / 40) * 8 + x;
  int rem = j % 40;
  int c  = rem / NQG;              // K-chunk 0..7
  int qg = rem % NQG;              // query group 0..4

  int tid = threadIdx.x;
  int w = tid >> 6, lane = tid & 63;
  __shared__ float Qs[QG][D_];         // 2 KB
  __shared__ float P[QG][CK];          // 8 KB
  __shared__ float pvred[4][QG][D_];   // 8 KB
  __shared__ int q0s[QG];
  if (tid < QG) q0s[tid] = Mtop[bh * U_ + qg * QG + tid];
  __syncthreads();
  for (int i = tid; i < QG * D_; i += 256) {
    int u = i >> 6, d = i & 63;
    Qs[u][d] = Q[((size_t)bh * L_ + q0s[u]) * D_ + d];
  }
  __syncthreads();

  // phase 1: scores. thread owns key kg = c*CK + tid.
  int kg = c * CK + tid;
  const float4* kr = (const float4*)(K + ((size_t)bh * L_ + kg) * D_);
  float4 kv[16];
#pragma unroll
  for (int j4 = 0; j4 < 16; ++j4) kv[j4] = kr[j4];
#pragma unroll
  for (int u = 0; u < QG; ++u) {
    float acc = 0.f;
#pragma unroll
    for (int j4 = 0; j4 < 16; ++j4) {
      float4 qv = *(const float4*)&Qs[u][j4 * 4];
      acc += qv.x * kv[j4].x + qv.y * kv[j4].y + qv.z * kv[j4].z + qv.w * kv[j4].w;
    }
    P[u][tid] = (kg <= q0s[u]) ? acc : -INFINITY;
  }
  __syncthreads();

  // phase 2: wave w softmaxes queries 2w, 2w+1 (chunk-local m, s)
#pragma unroll
  for (int uu = 0; uu < 2; ++uu) {
    int u = w * 2 + uu;
    float v0 = P[u][lane], v1 = P[u][lane + 64];
    float v2 = P[u][lane + 128], v3 = P[u][lane + 192];
    float m = fmaxf(fmaxf(v0, v1), fmaxf(v2, v3));
    for (int o = 32; o > 0; o >>= 1) m = fmaxf(m, __shfl_xor(m, o, 64));
    float e0 = (v0 == -INFINITY) ? 0.f : expf(v0 - m);
    float e1 = (v1 == -INFINITY) ? 0.f : expf(v1 - m);
    float e2 = (v2 == -INFINITY) ? 0.f : expf(v2 - m);
    float e3 = (v3 == -INFINITY) ? 0.f : expf(v3 - m);
    float s = e0 + e1 + e2 + e3;
    for (int o = 32; o > 0; o >>= 1) s += __shfl_xor(s, o, 64);
    P[u][lane] = e0; P[u][lane + 64] = e1;
    P[u][lane + 128] = e2; P[u][lane + 192] = e3;
    if (lane == 0) {
      int p = (bh * NCHUNK + c) * U_ + qg * QG + u;
      pm[p] = m; ps[p] = s;
    }
  }
  __syncthreads();

  // phase 3: wave w covers keys [c*CK + w*64, +64) for all 8 queries, lane=d
  const float* Vb = V + ((size_t)bh * L_ + c * CK + w * 64) * D_;
  float acc[QG];
#pragma unroll
  for (int u = 0; u < QG; ++u) acc[u] = 0.f;
  for (int k4 = 0; k4 < 16; ++k4) {
    float4 pv[QG];
#pragma unroll
    for (int u = 0; u < QG; ++u) pv[u] = *(const float4*)&P[u][w * 64 + k4 * 4];
    float va = Vb[(size_t)(k4 * 4 + 0) * D_ + lane];
    float vb = Vb[(size_t)(k4 * 4 + 1) * D_ + lane];
    float vc = Vb[(size_t)(k4 * 4 + 2) * D_ + lane];
    float vd = Vb[(size_t)(k4 * 4 + 3) * D_ + lane];
#pragma unroll
    for (int u = 0; u < QG; ++u)
      acc[u] += pv[u].x * va + pv[u].y * vb + pv[u].z * vc + pv[u].w * vd;
  }
#pragma unroll
  for (int u = 0; u < QG; ++u) pvred[w][u][lane] = acc[u];
  __syncthreads();
  // final: wave w writes queries 2w, 2w+1
#pragma unroll
  for (int uu = 0; uu < 2; ++uu) {
    int u = w * 2 + uu;
    float tot = pvred[0][u][lane] + pvred[1][u][lane] +
                pvred[2][u][lane] + pvred[3][u][lane];
    int p = (bh * NCHUNK + c) * U_ + qg * QG + u;
    pacc[(size_t)p * 64 + lane] = tot;
  }
}

// ---------------------------------------------------------------------------
// Kernel 4b: merge chunk partials, normalize, scatter into out.
// ---------------------------------------------------------------------------
__global__ __launch_bounds__(256) void k_attn_reduce(
    const float* __restrict__ pm, const float* __restrict__ ps,
    const float* __restrict__ pacc, const int* __restrict__ Mtop,
    float* __restrict__ out) {
  int g = blockIdx.x * 4 + (threadIdx.x >> 6);  // (bh, u) pair
  int lane = threadIdx.x & 63;
  int bh = g / U_, u = g % U_;
  int b = bh >> 3, h = bh & 7;
  int q0 = Mtop[bh * U_ + u];
  float pmv[NCHUNK];
  float M = -INFINITY;
#pragma unroll
  for (int c = 0; c < NCHUNK; ++c) {
    pmv[c] = pm[(bh * NCHUNK + c) * U_ + u];
    M = fmaxf(M, pmv[c]);
  }
  float T = 0.f, o = 0.f;
#pragma unroll
  for (int c = 0; c < NCHUNK; ++c) {
    float wgt = (pmv[c] == -INFINITY) ? 0.f : expf(pmv[c] - M);
    T += ps[(bh * NCHUNK + c) * U_ + u] * wgt;
    o += pacc[((size_t)(bh * NCHUNK + c) * U_ + u) * 64 + lane] * wgt;
  }
  out[(((size_t)b * L_ + q0) * H_ + h) * D_ + lane] = o / T;
}

extern "C" void kernel_launch(void* const* d_in, const int* in_sizes, int n_in,
                              void* d_out, int out_size, void* d_ws, size_t ws_size,
                              hipStream_t stream) {
  const float* Q = (const float*)d_in[0];
  const float* K = (const float*)d_in[1];
  const float* V = (const float*)d_in[2];
  const int* idxs = (const int*)d_in[3];
  float* out = (float*)d_out;

  char* ws = (char*)d_ws;
  float* M    = (float*)(ws + 0);              // 256 KB
  float* pfx  = (float*)(ws + 262144);         // 1 MB (32*128*64 floats)
  int*   Mtop = (int*)(ws + 1310720);          // 5 KB (pad to 8 KB)
  float* pm   = (float*)(ws + 1318912);        // 40 KB
  float* ps   = (float*)(ws + 1359872);        // 40 KB
  float* pacc = (float*)(ws + 1400832);        // 2.62 MB

  // 1) fused: cumsum phase A (prefix table, blocks 0..31) + M scores
  k_mcs<<<CSB + (B_ * H_ * L_) / 16, 1024, 0, stream>>>(Q, K, idxs, V, M, pfx);
  // 2) fused: top-k per head (blocks 0..31) + cumsum phase B (blocks 32..287)
  k_topk<<<CSB + PB, 1024, 0, stream>>>(M, V, pfx, Mtop, out);
  // 3) batched causal attention partials
  k_attn_part<<<B_ * H_ * NCHUNK * NQG, 256, 0, stream>>>(Q, K, V, Mtop, pm, ps, pacc);
  // 4) merge partials, overwrite selected rows
  k_attn_reduce<<<(B_ * H_ * U_) / 4, 256, 0, stream>>>(pm, ps, pacc, Mtop, out);
}